// Round 8
// baseline (20.565 us; speedup 1.0000x reference)
//
#include <hip/hip_runtime.h>

#define RW 8
#define LARGE_V 1e10f
#define NV 1024            // n (fixed problem shape)
#define NC 512             // m
#define SCALE 524288.0f    // 2^19 fixed-point scale (cumulative sum: ample headroom)
#define INV_SCALE (1.0f / 524288.0f)

// LDS-only barrier: wait local ops, raw s_barrier (no vmcnt drain, so global
// loads/stores issued in the loop stay in flight).
#define LDS_BARRIER() do { \
    asm volatile("s_waitcnt lgkmcnt(0)" ::: "memory"); \
    __builtin_amdgcn_s_barrier(); \
} while (0)

// Extraction only: one wave per H row -> RW ascending column indices.
__global__ __launch_bounds__(64) void setup_kernel(const int* __restrict__ H,
                                                   int* __restrict__ cols) {
    const int blk  = blockIdx.x;   // row
    const int lane = threadIdx.x;  // 0..63

    const int4* rp = (const int4*)(H + (size_t)blk * NV + lane * 16);
    int v[16];
    #pragma unroll
    for (int q = 0; q < 4; ++q) {
        int4 x = rp[q];
        v[q * 4 + 0] = x.x; v[q * 4 + 1] = x.y;
        v[q * 4 + 2] = x.z; v[q * 4 + 3] = x.w;
    }
    int cnt = 0;
    #pragma unroll
    for (int e = 0; e < 16; ++e) cnt += (v[e] != 0);
    int pre = cnt;                 // wave exclusive prefix-sum
    #pragma unroll
    for (int d = 1; d < 64; d <<= 1) {
        int o = __shfl_up(pre, d);
        if (lane >= d) pre += o;
    }
    pre -= cnt;
    int k = 0;
    #pragma unroll
    for (int e = 0; e < 16; ++e) {
        if (v[e] != 0) {
            if (pre + k < RW) cols[blk * RW + pre + k] = lane * 16 + e;
            ++k;
        }
    }
}

// One block (1024 threads) per batch element; two threads per check (4 edges
// each), partner combine via shfl_xor(,1). Soft values in REGISTERS; iacc is a
// cumulative (never-zeroed) fixed-point message sum:
//   soft_t[j] = soft0[j] + iacc_t[j] * INV_SCALE   (exact int accumulation).
// Labels cast is folded in here (fire-and-forget, overlaps iteration 0).
__global__ __launch_bounds__(1024) void bp_kernel(const float* __restrict__ soft_in,
                                                  const int* __restrict__ labels,
                                                  const int* __restrict__ cols,
                                                  const float* __restrict__ normalizer,
                                                  float* __restrict__ out,
                                                  int B, int niter) {
    __shared__ float s0[NV];
    __shared__ int   iacc[NV];

    const int b   = blockIdx.x;
    const int tid = threadIdx.x;
    const size_t BN = (size_t)B * NV;

    // issue all independent global loads up front (latencies overlap)
    const int4 a4    = *(const int4*)(cols + (tid >> 1) * RW + (tid & 1) * 4);
    const float msoft = soft_in[(size_t)b * NV + tid];
    const int   mlab  = labels[(size_t)b * NV + tid];
    const float norm  = log1pf(expf(normalizer[0]));  // softplus(normalizer)

    int c[4];
    c[0] = a4.x & (NV - 1); c[1] = a4.y & (NV - 1);
    c[2] = a4.z & (NV - 1); c[3] = a4.w & (NV - 1);

    // init: stage soft row, zero iacc, stream slice 0 + labels (fire-and-forget)
    s0[tid]   = msoft;
    iacc[tid] = 0;
    out[(size_t)b * NV + tid] = msoft;
    out[(size_t)(niter + 1) * BN + (size_t)b * NV + tid] = (float)mlab;
    LDS_BARRIER();

    float s0k[4];
    #pragma unroll
    for (int k = 0; k < 4; ++k) s0k[k] = s0[c[k]];

    // precompute check inputs for iteration 0 from register soft values
    float a[4]; unsigned int sb[4]; float m1, m2; unsigned int sxa;
    {
        float p[4]; unsigned int sx = 0; bool anyz = false;
        #pragma unroll
        for (int k = 0; k < 4; ++k) {
            float v = s0k[k];
            unsigned int bits = __float_as_uint(v);
            sb[k] = bits & 0x80000000u; sx ^= sb[k];
            float av = fabsf(v); a[k] = av;
            anyz = anyz || (av == 0.0f);
            p[k] = (av == 0.0f) ? LARGE_V : av;       // reference: proc
        }
        float l0 = fminf(p[0], p[1]), h0 = fmaxf(p[0], p[1]);
        float l1 = fminf(p[2], p[3]), h1 = fmaxf(p[2], p[3]);
        m1 = fminf(l0, l1);
        m2 = fminf(fmaxf(l0, l1), fminf(h0, h1));
        sxa = (sx & 0x80000000u) | (anyz ? 1u : 0u);  // bit31 sign-xor, bit0 anyz
    }

    for (int t = 0; t < niter; ++t) {
        // --- check phase: partner combine + 4 atomics (pure registers in) ---
        unsigned int oth = (unsigned int)__shfl_xor((int)sxa, 1);
        const unsigned int prodsign = (sxa ^ oth) & 0x80000000u;  // row sign product
        const bool zz = ((sxa | oth) & 1u) != 0u;                 // any zero in row
        float m1o = __shfl_xor(m1, 1);
        float m2o = __shfl_xor(m2, 1);
        const float mn1 = fminf(m1, m1o);
        const float mn2 = fminf(fmaxf(m1, m1o), fminf(m2, m2o));
        const int im1 = zz ? 0 : __float2int_rn(norm * mn1 * SCALE);
        const int im2 = zz ? 0 : __float2int_rn(norm * mn2 * SCALE);
        #pragma unroll
        for (int k = 0; k < 4; ++k) {
            int mag = (a[k] == mn1) ? im2 : im1;      // top-2 min-sum select
            int v   = ((prodsign ^ sb[k]) != 0u) ? -mag : mag;
            atomicAdd(&iacc[c[k]], v);                // native ds_add (cumulative)
        }
        LDS_BARRIER();

        // --- update phase: read back cumulative sums, recompute soft in regs ---
        int cum[4];
        #pragma unroll
        for (int k = 0; k < 4; ++k) cum[k] = iacc[c[k]];
        const int cumo = iacc[tid];
        const float svo = msoft + (float)cumo * INV_SCALE;
        out[(size_t)(t + 1) * BN + (size_t)b * NV + tid] = svo;  // fire-and-forget

        // precompute next iteration's check inputs (hidden under read latency)
        {
            float p[4]; unsigned int sx = 0; bool anyz = false;
            #pragma unroll
            for (int k = 0; k < 4; ++k) {
                float v = s0k[k] + (float)cum[k] * INV_SCALE;
                unsigned int bits = __float_as_uint(v);
                sb[k] = bits & 0x80000000u; sx ^= sb[k];
                float av = fabsf(v); a[k] = av;
                anyz = anyz || (av == 0.0f);
                p[k] = (av == 0.0f) ? LARGE_V : av;
            }
            float l0 = fminf(p[0], p[1]), h0 = fmaxf(p[0], p[1]);
            float l1 = fminf(p[2], p[3]), h1 = fmaxf(p[2], p[3]);
            m1 = fminf(l0, l1);
            m2 = fminf(fmaxf(l0, l1), fminf(h0, h1));
            sxa = (sx & 0x80000000u) | (anyz ? 1u : 0u);
        }
        LDS_BARRIER();
    }
}

extern "C" void kernel_launch(void* const* d_in, const int* in_sizes, int n_in,
                              void* d_out, int out_size, void* d_ws, size_t ws_size,
                              hipStream_t stream) {
    const float* soft_in    = (const float*)d_in[0];
    const int*   labels     = (const int*)d_in[1];
    const int*   H          = (const int*)d_in[2];
    const float* normalizer = (const float*)d_in[3];

    const int B     = in_sizes[0] / NV;          // 128
    const int niter = out_size / (B * NV) - 2;   // 10

    int* cols = (int*)d_ws;                      // NC*RW ints = 16 KB scratch

    setup_kernel<<<NC, 64, 0, stream>>>(H, cols);
    bp_kernel<<<B, 1024, 0, stream>>>(soft_in, labels, cols, normalizer,
                                      (float*)d_out, B, niter);
}